// Round 11
// baseline (335.813 us; speedup 1.0000x reference)
//
#include <hip/hip_runtime.h>
#include <hip/hip_cooperative_groups.h>
#include <math.h>

namespace cg = cooperative_groups;

#define Hd 264
#define Wd 480
#define HW (Hd * Wd)
#define NB 16
#define NC 9
#define KK 50
#define NPLANE (NB * NC)
#define NDET (NB * KK)
#define NK (NC * KK)               // 450
#define K1CH 8
#define NTASK (NPLANE * K1CH)      // 1152
#define F4PC (HW / 4 / K1CH)       // 3960
#define SLAB_CAP 512
#define SCAP 1024
#define FB_CAP 16384
#define GRID 1024
#define TB_F 0.998f
#define PI_F 3.14159274101257324f
#define TWO_PI_F 6.28318548202514648f

__device__ const float DIMM[9][3] = {
    {3.99331126f, 1.54370861f, 1.64175497f},
    {0.295f, 1.6f, 0.3175f},
    {1.34645161f, 1.55322581f, 0.3883871f},
    {2.503f, 1.72f, 1.077f},
    {9.1775f, 2.95f, 2.3425f},
    {10.3655102f, 3.31632653f, 2.45469388f},
    {6.016911083f, 3.412001685f, 2.2783185f},
    {4.824963f, 2.046904f, 1.78939f},
    {8.8040879f, 2.916193f, 2.07649252f}};

__device__ const float ACENT[4] = {0.0f, 1.57079637050628662f, 3.14159274101257324f, -1.57079637050628662f};

__device__ __forceinline__ unsigned long long mkkey(float v, unsigned int idx) {
    return ((unsigned long long)__float_as_uint(v) << 32) | (unsigned long long)(0xFFFFFFFFu - idx);
}

struct SharedP1 { unsigned long long sbuf[SLAB_CAP]; int scnt; };
struct SharedP2 {
    unsigned long long S[SCAP];
    int soff[K1CH + 1];
    int s_scnt, s_over;
    unsigned long long wmax[4];
    unsigned long long sprev;
};
struct SharedP3 { unsigned long long S[NK]; unsigned int sidx[NK]; };
struct SharedP4 { float s26[26]; float wred[4]; };
union SharedAll { SharedP1 p1; SharedP2 p2; SharedP3 p3; SharedP4 p4; };

// Single cooperative kernel: P1 threshold-scan -> P2 per-plane NMS-verify+rank
// -> P3 per-batch rank -> P4 per-det finalize, separated by grid.sync().
// Key = (value_bits<<32) | ~idx (heat>=0 -> bit order == value order; ~idx =
// jax.lax.top_k lower-index-wins tiebreak). All selection is keyed -> bit-exact.
__global__ __launch_bounds__(256, 4) void fused_all(const float* __restrict__ cls,
                                                    const float* __restrict__ regs,
                                                    const float* __restrict__ calib,
                                                    float* __restrict__ out,
                                                    unsigned long long* __restrict__ slabs,
                                                    int* __restrict__ slabCnt,
                                                    unsigned long long* __restrict__ planeKeys,
                                                    float* __restrict__ dScore,
                                                    int* __restrict__ dInd,
                                                    int* __restrict__ dCls,
                                                    unsigned long long* __restrict__ fbBuf,
                                                    int* __restrict__ fbCnt) {
    cg::grid_group grid = cg::this_grid();
    __shared__ SharedAll u;

    const int bid = blockIdx.x;
    const int tid = threadIdx.x;

    // ---------------- Phase 1: streaming threshold filter ----------------
    for (int task = bid; task < NTASK; task += GRID) {
        const int plane = task / K1CH;
        const int chunk = task - plane * K1CH;
        if (tid == 0) u.p1.scnt = 0;
        __syncthreads();

        const float4* hp4 = (const float4*)(cls + (size_t)plane * HW) + (size_t)chunk * F4PC;
        const unsigned int base = (unsigned int)(chunk * F4PC * 4);
        for (int q = tid; q < F4PC; q += 256) {
            const float4 v = hp4[q];
            const unsigned int i0 = base + 4u * (unsigned int)q;
            if (v.x >= TB_F) { const int p = atomicAdd(&u.p1.scnt, 1); if (p < SLAB_CAP) u.p1.sbuf[p] = mkkey(v.x, i0); }
            if (v.y >= TB_F) { const int p = atomicAdd(&u.p1.scnt, 1); if (p < SLAB_CAP) u.p1.sbuf[p] = mkkey(v.y, i0 + 1); }
            if (v.z >= TB_F) { const int p = atomicAdd(&u.p1.scnt, 1); if (p < SLAB_CAP) u.p1.sbuf[p] = mkkey(v.z, i0 + 2); }
            if (v.w >= TB_F) { const int p = atomicAdd(&u.p1.scnt, 1); if (p < SLAB_CAP) u.p1.sbuf[p] = mkkey(v.w, i0 + 3); }
        }
        __syncthreads();
        const int n = min(u.p1.scnt, SLAB_CAP);
        unsigned long long* dst = slabs + (size_t)task * SLAB_CAP;
        for (int j = tid; j < n; j += 256) dst[j] = u.p1.sbuf[j];
        if (tid == 0) slabCnt[task] = u.p1.scnt;  // raw (overflow-detectable)
        __syncthreads();
    }
    grid.sync();

    // ---------------- Phase 2: per-plane NMS-verify + exact top-50 ----------------
    if (bid < NPLANE) {
        const int plane = bid;
        const float* hp = cls + (size_t)plane * HW;

        if (tid == 0) { u.p2.s_scnt = 0; u.p2.s_over = 0; }
        __syncthreads();
        if (tid < K1CH) {
            const int c = slabCnt[plane * K1CH + tid];
            u.p2.soff[tid + 1] = min(c, SLAB_CAP);
            if (c > SLAB_CAP) atomicAdd(&u.p2.s_over, 1);
        }
        __syncthreads();
        if (tid == 0) {
            u.p2.soff[0] = 0;
            for (int c = 1; c <= K1CH; ++c) u.p2.soff[c] += u.p2.soff[c - 1];
        }
        __syncthreads();
        const int n = u.p2.soff[K1CH];

        // Verify each candidate with a direct 25-point window read (from global slabs).
        for (int j = tid; j < n; j += 256) {
            int lo = 0, hi = K1CH;
            while (hi - lo > 1) { const int mid = (lo + hi) >> 1; if (u.p2.soff[mid] <= j) lo = mid; else hi = mid; }
            const unsigned long long k = slabs[(size_t)(plane * K1CH + lo) * SLAB_CAP + (j - u.p2.soff[lo])];
            const unsigned int idx = 0xFFFFFFFFu - (unsigned int)(k & 0xFFFFFFFFull);
            const float v = __uint_as_float((unsigned int)(k >> 32));
            const int y = (int)idx / Wd, x = (int)idx - ((int)idx / Wd) * Wd;
            const int ylo = max(y - 2, 0), yhi = min(y + 2, Hd - 1);
            const int xlo = max(x - 2, 0), xhi = min(x + 2, Wd - 1);
            float wm = -INFINITY;
            for (int yy = ylo; yy <= yhi; ++yy)
                for (int xx = xlo; xx <= xhi; ++xx)
                    wm = fmaxf(wm, hp[yy * Wd + xx]);
            if (v == wm) {
                const int p = atomicAdd(&u.p2.s_scnt, 1);
                if (p < SCAP) u.p2.S[p] = k;
            }
        }
        __syncthreads();
        const int sc = u.p2.s_scnt;

        if (u.p2.s_over == 0 && sc >= KK && sc <= SCAP) {
            // Prefix-closed survivor set -> in-set rank == global rank. Exact.
            for (int idx = tid; idx < sc; idx += 256) {
                const unsigned long long k = u.p2.S[idx];
                int r = 0;
                for (int j = 0; j < sc; ++j) r += (u.p2.S[j] > k) ? 1 : 0;
                if (r < KK) planeKeys[plane * KK + r] = k;
            }
        } else {
            // Fallback (any-data correctness): brute-force full-plane NMS to global
            // scratch, then 50 rounds of keyed argmax. Never taken on this data.
            if (tid == 0) fbCnt[plane] = 0;
            for (int j = tid; j < KK; j += 256) planeKeys[plane * KK + j] = 0;
            __syncthreads();
            unsigned long long* fb = fbBuf + (size_t)plane * FB_CAP;
            for (int px = tid; px < HW; px += 256) {
                const float v = hp[px];
                const int y = px / Wd, x = px - (px / Wd) * Wd;
                const int ylo = max(y - 2, 0), yhi = min(y + 2, Hd - 1);
                const int xlo = max(x - 2, 0), xhi = min(x + 2, Wd - 1);
                float wm = -INFINITY;
                for (int yy = ylo; yy <= yhi; ++yy)
                    for (int xx = xlo; xx <= xhi; ++xx)
                        wm = fmaxf(wm, hp[yy * Wd + xx]);
                if (v == wm) {
                    const int p = atomicAdd(&fbCnt[plane], 1);
                    if (p < FB_CAP) fb[p] = mkkey(v, (unsigned int)px);
                }
            }
            __syncthreads();
            const int nn = min(fbCnt[plane], FB_CAP);
            unsigned long long prev = ~0ull;
            for (int it = 0; it < KK; ++it) {
                unsigned long long mk = 0;
                for (int j = tid; j < nn; j += 256) {
                    unsigned long long k = fb[j];
                    if (k == prev) { fb[j] = 0; k = 0; }
                    if (k > mk) mk = k;
                }
                for (int s = 32; s > 0; s >>= 1) {
                    const unsigned long long o = __shfl_down(mk, s);
                    if (o > mk) mk = o;
                }
                if ((tid & 63) == 0) u.p2.wmax[tid >> 6] = mk;
                __syncthreads();
                if (tid == 0) {
                    unsigned long long m = u.p2.wmax[0];
                    if (u.p2.wmax[1] > m) m = u.p2.wmax[1];
                    if (u.p2.wmax[2] > m) m = u.p2.wmax[2];
                    if (u.p2.wmax[3] > m) m = u.p2.wmax[3];
                    planeKeys[plane * KK + it] = m;
                    u.p2.sprev = m;
                }
                __syncthreads();
                prev = u.p2.sprev;
            }
        }
    }
    grid.sync();

    // ---------------- Phase 3: per-batch exact top-50 of 450 keys ----------------
    if (bid < NB) {
        const int b = bid;
        for (int j = tid; j < NK; j += 256) {
            const unsigned long long pk = planeKeys[b * NK + j];
            u.p3.sidx[j] = 0xFFFFFFFFu - (unsigned int)(pk & 0xFFFFFFFFull);
            u.p3.S[j] = (pk & 0xFFFFFFFF00000000ull) | (unsigned long long)(0xFFFFFFFFu - (unsigned int)j);
        }
        __syncthreads();
        for (int idx = tid; idx < NK; idx += 256) {
            const unsigned long long k = u.p3.S[idx];
            int r = 0;
            for (int j = 0; j < NK; ++j) r += (u.p3.S[j] > k) ? 1 : 0;
            if (r < KK) {
                dScore[b * KK + r] = __uint_as_float((unsigned int)(k >> 32));
                dInd[b * KK + r] = (int)u.p3.sidx[idx];
                dCls[b * KK + r] = idx / KK;
            }
        }
    }
    grid.sync();

    // ---------------- Phase 4: per-det finalize (block = detection) ----------------
    if (bid < NDET) {
        const int i = bid;
        const int ind0 = dInd[i];
        const int ind = (ind0 >= 0 && ind0 < HW) ? ind0 : 0;
        const int b = i / KK;

        if (tid < 26) {
            const int ch = (tid < 6) ? tid : tid + 16;  // 0-5, 22-24, 25-40, 41
            u.p4.s26[tid] = regs[(size_t)b * 46 * HW + (size_t)ch * HW + (size_t)ind];
        }

        // Batch-global segment-max over spatial index (reference segment_max).
        float m = -INFINITY;
        for (int j = tid; j < NDET; j += 256) {
            if (dInd[j] == ind0 && dScore[j] >= 0.29f) {
                m = fmaxf(m, (float)dCls[j] * 10000.0f - (float)j);
            }
        }
#pragma unroll
        for (int s = 32; s > 0; s >>= 1) m = fmaxf(m, __shfl_down(m, s));
        if ((tid & 63) == 0) u.p4.wred[tid >> 6] = m;
        __syncthreads();

        if (tid == 0) {
            m = fmaxf(fmaxf(u.p4.wred[0], u.p4.wred[1]), fmaxf(u.p4.wred[2], u.p4.wred[3]));
            const float* s = u.p4.s26;
            const int cls = dCls[i];
            const float score = dScore[i];
            const bool th = score >= 0.29f;
            const float key_i = th ? (float)cls * 10000.0f - (float)i : -INFINITY;
            const bool valid = th && (key_i == m);

            const float x = (float)(ind % Wd);
            const float y = (float)(ind / Wd);
            const float r0 = fmaxf(s[0], 0.0f), r1 = fmaxf(s[1], 0.0f);
            const float r2 = fmaxf(s[2], 0.0f), r3 = fmaxf(s[3], 0.0f);
            const float cx = x + s[4];
            const float cy = y + s[5];

            const float bx1 = fminf(fmaxf((cx - r0) * 4.0f, 0.0f), 1920.0f);
            const float by1 = fminf(fmaxf((cy - r1) * 4.0f, 0.0f), 1056.0f);
            const float bx2 = fminf(fmaxf((cx + r2) * 4.0f, 0.0f), 1920.0f);
            const float by2 = fminf(fmaxf((cy + r3) * 4.0f, 0.0f), 1056.0f);

            const float dim0 = expf(s[6]) * DIMM[cls][0];
            const float dim1 = expf(s[7]) * DIMM[cls][1];
            const float dim2 = expf(s[8]) * DIMM[cls][2];

            const float sig = 1.0f / (1.0f + expf(-s[25]));
            const float depth = fminf(fmaxf(1.0f / sig - 1.0f, 0.1f), 200.0f);

            const float fu = calib[0], cu = calib[2], fv = calib[5], cv = calib[6];
            const float bxo = calib[3] / -fu;
            const float byo = calib[7] / -fv;
            const float locx = (cx * 4.0f - cu) * depth / fu + bxo;
            const float locy = (cy * 4.0f - cv) * depth / fv + byo;

            float best = -INFINITY;
            int bidx = 0;
#pragma unroll
            for (int t = 0; t < 4; ++t) {
                const float l0 = s[9 + 2 * t], l1 = s[9 + 2 * t + 1];
                const float mm = fmaxf(l0, l1);
                const float p1 = expf(l1 - mm) / (expf(l0 - mm) + expf(l1 - mm));
                if (p1 > best) { best = p1; bidx = t; }
            }
            const float sel0 = s[17 + 2 * bidx], sel1 = s[17 + 2 * bidx + 1];
            float alpha = atanf(sel0 / sel1) + ACENT[bidx];
            const float ray = atanf(locx / depth);
            float roty = alpha + ray;
            if (roty > PI_F) roty -= TWO_PI_F;
            if (roty < -PI_F) roty += TWO_PI_F;
            if (alpha > PI_F) alpha -= TWO_PI_F;
            if (alpha < -PI_F) alpha += TWO_PI_F;

            float* o = out + (size_t)i * 14;
            o[0] = bx1; o[1] = by1; o[2] = bx2; o[3] = by2;
            o[4] = dim0; o[5] = dim1; o[6] = dim2;
            o[7] = depth;
            o[8] = locx; o[9] = locy; o[10] = depth;
            o[11] = roty; o[12] = alpha;
            o[13] = score;
            out[NDET * 14 + i] = valid ? 1.0f : 0.0f;
            out[NDET * 15 + i] = (float)cls;
        }
    }
}

extern "C" void kernel_launch(void* const* d_in, const int* in_sizes, int n_in,
                              void* d_out, int out_size, void* d_ws, size_t ws_size,
                              hipStream_t stream) {
    const float* cls = (const float*)d_in[0];
    const float* regs = (const float*)d_in[1];
    const float* calib = (const float*)d_in[2];
    float* out = (float*)d_out;
    char* ws = (char*)d_ws;

    // ws layout (all regions rewritten each launch before being read)
    int* slabCnt = (int*)ws;                                          // 1152*4 B (pad 8K)
    unsigned long long* slabs = (unsigned long long*)(ws + 8192);     // 1152*512*8 = 4,718,592 B
    char* t1 = ws + 8192 + 4718592;
    unsigned long long* planeKeys = (unsigned long long*)t1;          // 57,600 B
    float* dScore = (float*)(t1 + 57600);                             // 3200 B
    int* dInd = (int*)(t1 + 60800);                                   // 3200 B
    int* dCls = (int*)(t1 + 64000);                                   // 3200 B
    int* fbCnt = (int*)(t1 + 67200);                                  // 576 B (pad 1K)
    unsigned long long* fbBuf = (unsigned long long*)(t1 + 68224);    // 144*16384*8 = 18,874,368 B

    void* args[] = {(void*)&cls, (void*)&regs, (void*)&calib, (void*)&out,
                    (void*)&slabs, (void*)&slabCnt, (void*)&planeKeys,
                    (void*)&dScore, (void*)&dInd, (void*)&dCls,
                    (void*)&fbBuf, (void*)&fbCnt};
    hipLaunchCooperativeKernel((void*)fused_all, dim3(GRID), dim3(256), args, 0, stream);
}